// Round 1
// baseline (815.060 us; speedup 1.0000x reference)
//
#include <hip/hip_runtime.h>
#include <hip/hip_bf16.h>

// Problem: N=16384 queries, C=1024 classes, D=4096.
// sims = l2norm(hvs) @ l2norm(am)^T ; preds = argmax_c sims ; eta = (sims[:,1]-sims[:,0])/4 + 0.5
// Strategy: bf16-split GEMM (hi/lo, 3 MFMA passes) for f32-level precision on the matrix pipe.

#define NQ 16384
#define NC 1024
#define DK 4096

typedef __attribute__((ext_vector_type(8))) short short8;
typedef __attribute__((ext_vector_type(4))) float f32x4;

__device__ __forceinline__ unsigned short bf16_rne(float x) {
    unsigned int u = __float_as_uint(x);
    u += 0x7FFFu + ((u >> 16) & 1u);
    return (unsigned short)(u >> 16);
}
__device__ __forceinline__ float bf16_f32(unsigned short h) {
    return __uint_as_float(((unsigned int)h) << 16);
}

// ---------------- row 1/max(norm,eps) ----------------
__global__ void __launch_bounds__(256) row_rnorm_kernel(const float* __restrict__ x,
                                                        float* __restrict__ rn) {
    const int row = blockIdx.x;
    const float4* x4 = (const float4*)x + (size_t)row * (DK / 4);
    float ss = 0.f;
#pragma unroll
    for (int i = 0; i < 4; ++i) {
        float4 v = x4[threadIdx.x + i * 256];
        ss += v.x * v.x + v.y * v.y + v.z * v.z + v.w * v.w;
    }
#pragma unroll
    for (int off = 32; off; off >>= 1) ss += __shfl_xor(ss, off, 64);
    __shared__ float wsum[4];
    const int lane = threadIdx.x & 63, w = threadIdx.x >> 6;
    if (lane == 0) wsum[w] = ss;
    __syncthreads();
    if (threadIdx.x == 0) {
        float t = wsum[0] + wsum[1] + wsum[2] + wsum[3];
        rn[row] = 1.0f / fmaxf(sqrtf(t), 1e-8f);
    }
}

// ---------------- bf16-split GEMM: dots = hvs @ am^T ----------------
// 128x128 tile, BK=32, 4 waves (each 64x64), mfma_f32_16x16x32_bf16.
// LDS tiles padded to 40 shorts/row (80B stride) -> ~2-way max bank aliasing on b128 reads.
__global__ void __launch_bounds__(256) gemm_split_kernel(const float* __restrict__ A,
                                                         const float* __restrict__ B,
                                                         float* __restrict__ dots) {
    __shared__ __align__(16) unsigned short Ah[128][40];
    __shared__ __align__(16) unsigned short Al[128][40];
    __shared__ __align__(16) unsigned short Bh[128][40];
    __shared__ __align__(16) unsigned short Bl[128][40];

    const int tid = threadIdx.x;
    const int bx = blockIdx.x;   // class-block 0..7
    const int by = blockIdx.y;   // query-block 0..127
    const int lane = tid & 63;
    const int w = tid >> 6;      // wave 0..3
    const int wm = w >> 1;       // 0..1
    const int wn = w & 1;        // 0..1

    const float4* A4 = (const float4*)A;
    const float4* B4 = (const float4*)B;

    f32x4 acc[4][4];
#pragma unroll
    for (int m = 0; m < 4; ++m)
#pragma unroll
        for (int n = 0; n < 4; ++n) acc[m][n] = (f32x4){0.f, 0.f, 0.f, 0.f};

    float4 pa[4], pb[4];

    // staging geometry: 128x32 f32 tile = 1024 float4; thread handles 4 of them
    int srow[4], sc4[4];
#pragma unroll
    for (int i = 0; i < 4; ++i) {
        int q = i * 256 + tid;
        srow[i] = q >> 3;
        sc4[i] = q & 7;
    }

    auto load_tiles = [&](int kt) {
#pragma unroll
        for (int i = 0; i < 4; ++i) {
            pa[i] = A4[(size_t)(by * 128 + srow[i]) * (DK / 4) + kt * 8 + sc4[i]];
            pb[i] = B4[(size_t)(bx * 128 + srow[i]) * (DK / 4) + kt * 8 + sc4[i]];
        }
    };
    auto convert_store = [&]() {
#pragma unroll
        for (int i = 0; i < 4; ++i) {
            const int row = srow[i];
            const int c = sc4[i] * 4;
            {
                float4 v = pa[i];
                unsigned short h0 = bf16_rne(v.x), h1 = bf16_rne(v.y),
                               h2 = bf16_rne(v.z), h3 = bf16_rne(v.w);
                unsigned short l0 = bf16_rne(v.x - bf16_f32(h0)),
                               l1 = bf16_rne(v.y - bf16_f32(h1)),
                               l2 = bf16_rne(v.z - bf16_f32(h2)),
                               l3 = bf16_rne(v.w - bf16_f32(h3));
                *(uint2*)&Ah[row][c] =
                    make_uint2((unsigned)h0 | ((unsigned)h1 << 16), (unsigned)h2 | ((unsigned)h3 << 16));
                *(uint2*)&Al[row][c] =
                    make_uint2((unsigned)l0 | ((unsigned)l1 << 16), (unsigned)l2 | ((unsigned)l3 << 16));
            }
            {
                float4 v = pb[i];
                unsigned short h0 = bf16_rne(v.x), h1 = bf16_rne(v.y),
                               h2 = bf16_rne(v.z), h3 = bf16_rne(v.w);
                unsigned short l0 = bf16_rne(v.x - bf16_f32(h0)),
                               l1 = bf16_rne(v.y - bf16_f32(h1)),
                               l2 = bf16_rne(v.z - bf16_f32(h2)),
                               l3 = bf16_rne(v.w - bf16_f32(h3));
                *(uint2*)&Bh[row][c] =
                    make_uint2((unsigned)h0 | ((unsigned)h1 << 16), (unsigned)h2 | ((unsigned)h3 << 16));
                *(uint2*)&Bl[row][c] =
                    make_uint2((unsigned)l0 | ((unsigned)l1 << 16), (unsigned)l2 | ((unsigned)l3 << 16));
            }
        }
    };

    load_tiles(0);
    convert_store();
    __syncthreads();

    const int r0 = lane & 15;
    const int kb = (lane >> 4) * 8;

    for (int kt = 0; kt < DK / 32; ++kt) {
        short8 a_h[4], a_l[4], b_h[4], b_l[4];
#pragma unroll
        for (int m = 0; m < 4; ++m) {
            const int row = wm * 64 + m * 16 + r0;
            a_h[m] = *(const short8*)&Ah[row][kb];
            a_l[m] = *(const short8*)&Al[row][kb];
        }
#pragma unroll
        for (int n = 0; n < 4; ++n) {
            const int col = wn * 64 + n * 16 + r0;
            b_h[n] = *(const short8*)&Bh[col][kb];
            b_l[n] = *(const short8*)&Bl[col][kb];
        }

        if (kt + 1 < DK / 32) load_tiles(kt + 1);  // in flight during MFMA phase

#pragma unroll
        for (int m = 0; m < 4; ++m)
#pragma unroll
            for (int n = 0; n < 4; ++n) {
                acc[m][n] = __builtin_amdgcn_mfma_f32_16x16x32_bf16(a_h[m], b_h[n], acc[m][n], 0, 0, 0);
                acc[m][n] = __builtin_amdgcn_mfma_f32_16x16x32_bf16(a_h[m], b_l[n], acc[m][n], 0, 0, 0);
                acc[m][n] = __builtin_amdgcn_mfma_f32_16x16x32_bf16(a_l[m], b_h[n], acc[m][n], 0, 0, 0);
            }

        __syncthreads();
        if (kt + 1 < DK / 32) {
            convert_store();
        }
        __syncthreads();
    }

    // epilogue: C/D layout col=lane&15, row=(lane>>4)*4+j  [m89-verified]
    const int rg = lane >> 4;
#pragma unroll
    for (int m = 0; m < 4; ++m)
#pragma unroll
        for (int n = 0; n < 4; ++n) {
            const int col = bx * 128 + wn * 64 + n * 16 + r0;
#pragma unroll
            for (int j = 0; j < 4; ++j) {
                const int row = by * 128 + wm * 64 + m * 16 + rg * 4 + j;
                dots[(size_t)row * NC + col] = acc[m][n][j];
            }
        }
}

// ---------------- argmax + eta ----------------
__global__ void __launch_bounds__(256) argmax_eta_kernel(const float* __restrict__ dots,
                                                         const float* __restrict__ hrn,
                                                         const float* __restrict__ arn,
                                                         float* __restrict__ out) {
    const int lane = threadIdx.x & 63;
    const int row = blockIdx.x * 4 + (threadIdx.x >> 6);
    const float* drow = dots + (size_t)row * NC;

    float best = -3.402823466e+38f;
    int bidx = 0x7FFFFFFF;
#pragma unroll
    for (int it = 0; it < NC / 64; ++it) {
        const int c = lane + it * 64;
        const float v = drow[c] * arn[c];
        if (v > best) { best = v; bidx = c; }
    }
#pragma unroll
    for (int off = 1; off < 64; off <<= 1) {
        const float ov = __shfl_xor(best, off, 64);
        const int oi = __shfl_xor(bidx, off, 64);
        if (ov > best || (ov == best && oi < bidx)) { best = ov; bidx = oi; }
    }
    if (lane == 0) {
        out[row] = (float)bidx;
        const float h = hrn[row];
        const float s0 = drow[0] * arn[0] * h;
        const float s1 = drow[1] * arn[1] * h;
        out[NQ + row] = (s1 - s0) * 0.25f + 0.5f;
    }
}

extern "C" void kernel_launch(void* const* d_in, const int* in_sizes, int n_in,
                              void* d_out, int out_size, void* d_ws, size_t ws_size,
                              hipStream_t stream) {
    const float* hvs = (const float*)d_in[0];  // [16384,4096]
    const float* am  = (const float*)d_in[1];  // [1024,4096]
    float* out = (float*)d_out;                // [16384 preds | 16384 eta]

    float* dots = (float*)d_ws;                      // 16384*1024 f32 = 64 MB
    float* hrn  = dots + (size_t)NQ * NC;            // 16384
    float* arn  = hrn + NQ;                          // 1024

    row_rnorm_kernel<<<NQ, 256, 0, stream>>>(hvs, hrn);
    row_rnorm_kernel<<<NC, 256, 0, stream>>>(am, arn);
    gemm_split_kernel<<<dim3(8, 128), 256, 0, stream>>>(hvs, am, dots);
    argmax_eta_kernel<<<NQ / 4, 256, 0, stream>>>(dots, hrn, arn, out);
}

// Round 2
// 597.421 us; speedup vs baseline: 1.3643x; 1.3643x over previous
//
#include <hip/hip_runtime.h>
#include <hip/hip_bf16.h>

// N=16384 queries, C=1024 classes, D=4096.
// sims = l2norm(hvs) @ l2norm(am)^T ; preds = argmax ; eta = (sims[:,1]-sims[:,0])/4 + 0.5
// R2: pre-pass fuses row-norm + bf16 hi/lo split (done ONCE); GEMM is pure
// global_load_lds-staged 3-term bf16 MFMA (no conversion VALU in the loop).

#define NQ 16384
#define NC 1024
#define DK 4096
#define BK 32

typedef __attribute__((ext_vector_type(8))) short short8;
typedef __attribute__((ext_vector_type(4))) float f32x4;
typedef unsigned short ushort_t;

__device__ __forceinline__ unsigned short bf16_rne(float x) {
    unsigned int u = __float_as_uint(x);
    u += 0x7FFFu + ((u >> 16) & 1u);
    return (unsigned short)(u >> 16);
}
__device__ __forceinline__ float bf16_f32(unsigned short h) {
    return __uint_as_float(((unsigned int)h) << 16);
}

#define GLDS(g, l)                                                                       \
    __builtin_amdgcn_global_load_lds((const __attribute__((address_space(1))) void*)(g), \
                                     (__attribute__((address_space(3))) void*)(l), 16, 0, 0)

// ---------------- fused row-norm + normalize + bf16 hi/lo split ----------------
// one block per row; thread t owns cols [t*16, t*16+16)
__global__ void __launch_bounds__(256) norm_split_kernel(const float* __restrict__ x,
                                                         ushort_t* __restrict__ hi,
                                                         ushort_t* __restrict__ lo) {
    const int row = blockIdx.x;
    const int tid = threadIdx.x;
    const float4* x4 = (const float4*)(x + (size_t)row * DK);

    float4 v[4];
    float ss = 0.f;
#pragma unroll
    for (int i = 0; i < 4; ++i) {
        v[i] = x4[tid * 4 + i];
        ss += v[i].x * v[i].x + v[i].y * v[i].y + v[i].z * v[i].z + v[i].w * v[i].w;
    }
#pragma unroll
    for (int off = 32; off; off >>= 1) ss += __shfl_xor(ss, off, 64);
    __shared__ float wsum[4];
    const int lane = tid & 63, w = tid >> 6;
    if (lane == 0) wsum[w] = ss;
    __syncthreads();
    const float tot = wsum[0] + wsum[1] + wsum[2] + wsum[3];
    const float r = 1.0f / fmaxf(sqrtf(tot), 1e-8f);

    ushort_t hbuf[16], lbuf[16];
#pragma unroll
    for (int i = 0; i < 4; ++i) {
        const float xs[4] = {v[i].x * r, v[i].y * r, v[i].z * r, v[i].w * r};
#pragma unroll
        for (int j = 0; j < 4; ++j) {
            const unsigned short h = bf16_rne(xs[j]);
            hbuf[i * 4 + j] = h;
            lbuf[i * 4 + j] = bf16_rne(xs[j] - bf16_f32(h));
        }
    }
    ushort_t* hp = hi + (size_t)row * DK + tid * 16;
    ushort_t* lp = lo + (size_t)row * DK + tid * 16;
    *(short8*)hp = *(short8*)hbuf;
    *(short8*)(hp + 8) = *(short8*)(hbuf + 8);
    *(short8*)lp = *(short8*)lbuf;
    *(short8*)(lp + 8) = *(short8*)(lbuf + 8);
}

// ---------------- 3-term split GEMM, m97 structure ----------------
// 128x128 tile, BK=32, 4 waves (64x64 each), global_load_lds(16B) staging,
// XOR slot-swizzle (slot ^= (row>>1)&3) pre-applied on the GLOBAL source so the
// linear LDS dest ends up swizzled; ds_read applies the same XOR.
__global__ void __launch_bounds__(256) gemm_pre_kernel(const ushort_t* __restrict__ Ah,
                                                       const ushort_t* __restrict__ Al,
                                                       const ushort_t* __restrict__ Bh,
                                                       const ushort_t* __restrict__ Bl,
                                                       float* __restrict__ dots) {
    __shared__ __align__(16) ushort_t lAh[128 * 32];
    __shared__ __align__(16) ushort_t lAl[128 * 32];
    __shared__ __align__(16) ushort_t lBh[128 * 32];
    __shared__ __align__(16) ushort_t lBl[128 * 32];

    const int tid = threadIdx.x;
    const int lane = tid & 63;
    const int w = tid >> 6;
    const int wm = w >> 1;
    const int wn = w & 1;
    const int bx = blockIdx.x;  // class-block 0..7
    const int by = blockIdx.y;  // query-block

    // staging geometry: per operand tile = 128 rows x 4 slots(16B) = 512 chunks; 2/thread
    const int q0 = tid, q1 = tid + 256;
    const int row0 = q0 >> 2, row1 = q1 >> 2;
    const int s0 = (q0 & 3) ^ ((row0 >> 1) & 3);
    const int s1 = (q1 & 3) ^ ((row1 >> 1) & 3);
    const size_t offA0 = (size_t)(by * 128 + row0) * DK + s0 * 8;
    const size_t offA1 = (size_t)(by * 128 + row1) * DK + s1 * 8;
    const size_t offB0 = (size_t)(bx * 128 + row0) * DK + s0 * 8;
    const size_t offB1 = (size_t)(bx * 128 + row1) * DK + s1 * 8;

    f32x4 acc[4][4];
#pragma unroll
    for (int m = 0; m < 4; ++m)
#pragma unroll
        for (int n = 0; n < 4; ++n) acc[m][n] = (f32x4){0.f, 0.f, 0.f, 0.f};

    const int r0 = lane & 15;
    const int sl = lane >> 4;            // logical k-octet 0..3
    const int ph = sl ^ ((r0 >> 1) & 3); // physical slot after swizzle (same for all rows read)

    for (int kt = 0; kt < DK / BK; ++kt) {
        const int ko = kt * BK;
        GLDS(Ah + offA0 + ko, &lAh[q0 * 8]);
        GLDS(Ah + offA1 + ko, &lAh[q1 * 8]);
        GLDS(Al + offA0 + ko, &lAl[q0 * 8]);
        GLDS(Al + offA1 + ko, &lAl[q1 * 8]);
        GLDS(Bh + offB0 + ko, &lBh[q0 * 8]);
        GLDS(Bh + offB1 + ko, &lBh[q1 * 8]);
        GLDS(Bl + offB0 + ko, &lBl[q0 * 8]);
        GLDS(Bl + offB1 + ko, &lBl[q1 * 8]);
        asm volatile("s_waitcnt vmcnt(0)" ::: "memory");
        __syncthreads();

        short8 ah[4], al[4], bh[4], bl[4];
#pragma unroll
        for (int m = 0; m < 4; ++m) {
            const int row = wm * 64 + m * 16 + r0;
            ah[m] = *(const short8*)&lAh[row * 32 + ph * 8];
            al[m] = *(const short8*)&lAl[row * 32 + ph * 8];
        }
#pragma unroll
        for (int n = 0; n < 4; ++n) {
            const int col = wn * 64 + n * 16 + r0;
            bh[n] = *(const short8*)&lBh[col * 32 + ph * 8];
            bl[n] = *(const short8*)&lBl[col * 32 + ph * 8];
        }
#pragma unroll
        for (int m = 0; m < 4; ++m)
#pragma unroll
            for (int n = 0; n < 4; ++n) {
                acc[m][n] = __builtin_amdgcn_mfma_f32_16x16x32_bf16(ah[m], bh[n], acc[m][n], 0, 0, 0);
                acc[m][n] = __builtin_amdgcn_mfma_f32_16x16x32_bf16(ah[m], bl[n], acc[m][n], 0, 0, 0);
                acc[m][n] = __builtin_amdgcn_mfma_f32_16x16x32_bf16(al[m], bh[n], acc[m][n], 0, 0, 0);
            }
        __syncthreads();
    }

    // epilogue: C/D layout col=lane&15, row=(lane>>4)*4+j  [m89-verified]
    const int rg = lane >> 4;
#pragma unroll
    for (int m = 0; m < 4; ++m)
#pragma unroll
        for (int n = 0; n < 4; ++n) {
            const int col = bx * 128 + wn * 64 + n * 16 + r0;
#pragma unroll
            for (int j = 0; j < 4; ++j) {
                const int row = by * 128 + wm * 64 + m * 16 + rg * 4 + j;
                dots[(size_t)row * NC + col] = acc[m][n][j];
            }
        }
}

// ---------------- argmax + eta (dots are final sims) ----------------
__global__ void __launch_bounds__(256) argmax_eta_kernel(const float* __restrict__ dots,
                                                         float* __restrict__ out,
                                                         int row_base) {
    const int lane = threadIdx.x & 63;
    const int lrow = blockIdx.x * 4 + (threadIdx.x >> 6);
    const float* drow = dots + (size_t)lrow * NC;

    float best = -3.402823466e+38f;
    int bidx = 0x7FFFFFFF;
#pragma unroll
    for (int it = 0; it < NC / 64; ++it) {
        const int c = lane + it * 64;
        const float v = drow[c];
        if (v > best) { best = v; bidx = c; }
    }
#pragma unroll
    for (int off = 1; off < 64; off <<= 1) {
        const float ov = __shfl_xor(best, off, 64);
        const int oi = __shfl_xor(bidx, off, 64);
        if (ov > best || (ov == best && oi < bidx)) { best = ov; bidx = oi; }
    }
    if (lane == 0) {
        const int row = row_base + lrow;
        out[row] = (float)bidx;
        out[NQ + row] = (drow[1] - drow[0]) * 0.25f + 0.5f;
    }
}

extern "C" void kernel_launch(void* const* d_in, const int* in_sizes, int n_in,
                              void* d_out, int out_size, void* d_ws, size_t ws_size,
                              hipStream_t stream) {
    const float* hvs = (const float*)d_in[0];  // [16384,4096]
    const float* am  = (const float*)d_in[1];  // [1024,4096]
    float* out = (float*)d_out;

    // ws layout: Bh | Bl | Ah(chunk) | Al(chunk) | dots(chunk)
    const size_t bElems = (size_t)NC * DK;
    int nch = 8;
    for (int c = 1; c <= 8; c <<= 1) {
        const size_t R = NQ / c;
        const size_t need = 2 * bElems * 2 + 2 * R * DK * 2 + R * NC * 4;
        if (need <= ws_size) { nch = c; break; }
    }
    const size_t R = NQ / nch;

    ushort_t* Bh = (ushort_t*)d_ws;
    ushort_t* Bl = Bh + bElems;
    ushort_t* Ah = Bl + bElems;
    ushort_t* Al = Ah + R * DK;
    float* dots = (float*)(Al + R * DK);

    norm_split_kernel<<<NC, 256, 0, stream>>>(am, Bh, Bl);
    for (int c = 0; c < nch; ++c) {
        norm_split_kernel<<<(int)R, 256, 0, stream>>>(hvs + (size_t)c * R * DK, Ah, Al);
        gemm_pre_kernel<<<dim3(8, (int)(R / 128)), 256, 0, stream>>>(Ah, Al, Bh, Bl, dots);
        argmax_eta_kernel<<<(int)(R / 4), 256, 0, stream>>>(dots, out, (int)(c * R));
    }
}

// Round 3
// 478.799 us; speedup vs baseline: 1.7023x; 1.2477x over previous
//
#include <hip/hip_runtime.h>
#include <hip/hip_bf16.h>

// N=16384 queries, C=1024 classes, D=4096.
// sims = l2norm(hvs) @ l2norm(am)^T ; preds = argmax ; eta = (sims[:,1]-sims[:,0])/4 + 0.5
// R3: 256x256-tile 8-wave GEMM, dbuf + issue-early staging + counted vmcnt(8)
// (T3-minimum), bijective XCD swizzle for A-panel L2 reuse, argmax fused into
// the GEMM epilogue (no dots matrix in HBM).

#define NQ 16384
#define NC 1024
#define DK 4096
#define BKS 32

typedef __attribute__((ext_vector_type(8))) short short8;
typedef __attribute__((ext_vector_type(4))) float f32x4;
typedef unsigned short ushort_t;

__device__ __forceinline__ unsigned short bf16_rne(float x) {
    unsigned int u = __float_as_uint(x);
    u += 0x7FFFu + ((u >> 16) & 1u);
    return (unsigned short)(u >> 16);
}
__device__ __forceinline__ float bf16_f32(unsigned short h) {
    return __uint_as_float(((unsigned int)h) << 16);
}

#define GLDS(g, l)                                                                       \
    __builtin_amdgcn_global_load_lds((const __attribute__((address_space(1))) void*)(g), \
                                     (__attribute__((address_space(3))) void*)(l), 16, 0, 0)

// ---------------- fused row-norm + normalize + bf16 hi/lo split ----------------
__global__ void __launch_bounds__(256) norm_split_kernel(const float* __restrict__ x,
                                                         ushort_t* __restrict__ hi,
                                                         ushort_t* __restrict__ lo) {
    const int row = blockIdx.x;
    const int tid = threadIdx.x;
    const float4* x4 = (const float4*)(x + (size_t)row * DK);

    float4 v[4];
    float ss = 0.f;
#pragma unroll
    for (int i = 0; i < 4; ++i) {
        v[i] = x4[tid * 4 + i];
        ss += v[i].x * v[i].x + v[i].y * v[i].y + v[i].z * v[i].z + v[i].w * v[i].w;
    }
#pragma unroll
    for (int off = 32; off; off >>= 1) ss += __shfl_xor(ss, off, 64);
    __shared__ float wsum[4];
    const int lane = tid & 63, w = tid >> 6;
    if (lane == 0) wsum[w] = ss;
    __syncthreads();
    const float tot = wsum[0] + wsum[1] + wsum[2] + wsum[3];
    const float r = 1.0f / fmaxf(sqrtf(tot), 1e-8f);

    ushort_t hbuf[16], lbuf[16];
#pragma unroll
    for (int i = 0; i < 4; ++i) {
        const float xs[4] = {v[i].x * r, v[i].y * r, v[i].z * r, v[i].w * r};
#pragma unroll
        for (int j = 0; j < 4; ++j) {
            const unsigned short h = bf16_rne(xs[j]);
            hbuf[i * 4 + j] = h;
            lbuf[i * 4 + j] = bf16_rne(xs[j] - bf16_f32(h));
        }
    }
    ushort_t* hp = hi + (size_t)row * DK + tid * 16;
    ushort_t* lp = lo + (size_t)row * DK + tid * 16;
    *(short8*)hp = *(short8*)hbuf;
    *(short8*)(hp + 8) = *(short8*)(hbuf + 8);
    *(short8*)lp = *(short8*)lbuf;
    *(short8*)(lp + 8) = *(short8*)(lbuf + 8);
}

// ---------------- 256x256 3-term split GEMM, fused argmax epilogue ----------------
// 8 waves (2M x 4N), per-wave 128x64. dbuf LDS (128 KB), issue-early stage,
// counted vmcnt(8), raw s_barrier. XOR slot-swizzle (ps = sl ^ ((row>>1)&3))
// pre-applied on the GLOBAL source (linear gload_lds dest), same XOR on ds_read.
__global__ void __launch_bounds__(512, 2) gemm_fused_kernel(const ushort_t* __restrict__ Ah,
                                                            const ushort_t* __restrict__ Al,
                                                            const ushort_t* __restrict__ Bh,
                                                            const ushort_t* __restrict__ Bl,
                                                            float2* __restrict__ cand,
                                                            float* __restrict__ s01) {
    __shared__ __align__(16) ushort_t lA[2][2][256 * BKS];  // [buf][hi/lo] 64 KB
    __shared__ __align__(16) ushort_t lB[2][2][256 * BKS];  // 64 KB

    const int tid = threadIdx.x;
    const int lane = tid & 63;
    const int w = tid >> 6;   // 0..7
    const int wm = w >> 2;    // 0..1
    const int wn = w & 3;     // 0..3

    // bijective XCD swizzle: the 4 bx-blocks sharing a by-panel land on one XCD
    const int id = blockIdx.x;      // 0..255
    const int xcd = id & 7;
    const int slot = id >> 3;       // 0..31
    const int by = xcd * 8 + (slot >> 2);  // 0..63
    const int bx = slot & 3;               // 0..3

    // staging: per matrix-half, tile = 256 rows x 4 slots(16B) = 1024 chunks; 2/thread
    const int q0 = tid, q1 = tid + 512;
    const int row0 = q0 >> 2, row1 = q1 >> 2;
    const int gs0 = (q0 & 3) ^ ((row0 >> 1) & 3);
    const int gs1 = (q1 & 3) ^ ((row1 >> 1) & 3);
    const size_t offA0 = (size_t)(by * 256 + row0) * DK + gs0 * 8;
    const size_t offA1 = (size_t)(by * 256 + row1) * DK + gs1 * 8;
    const size_t offB0 = (size_t)(bx * 256 + row0) * DK + gs0 * 8;
    const size_t offB1 = (size_t)(bx * 256 + row1) * DK + gs1 * 8;

    f32x4 acc[8][4];
#pragma unroll
    for (int m = 0; m < 8; ++m)
#pragma unroll
        for (int n = 0; n < 4; ++n) acc[m][n] = (f32x4){0.f, 0.f, 0.f, 0.f};

    const int r0 = lane & 15;
    const int rg = lane >> 4;  // k-octet

    // LDS frag offsets (shorts), swizzle-matched to the staged layout
    int aoff[8], boff[4];
#pragma unroll
    for (int m = 0; m < 8; ++m) {
        const int row = wm * 128 + m * 16 + r0;
        aoff[m] = row * BKS + (rg ^ ((row >> 1) & 3)) * 8;
    }
#pragma unroll
    for (int n = 0; n < 4; ++n) {
        const int col = wn * 64 + n * 16 + r0;
        boff[n] = col * BKS + (rg ^ ((col >> 1) & 3)) * 8;
    }

    auto stage = [&](int buf, int kt) {
        const size_t ko = (size_t)kt * BKS;
        GLDS(Ah + offA0 + ko, &lA[buf][0][q0 * 8]);
        GLDS(Al + offA0 + ko, &lA[buf][1][q0 * 8]);
        GLDS(Bh + offB0 + ko, &lB[buf][0][q0 * 8]);
        GLDS(Bl + offB0 + ko, &lB[buf][1][q0 * 8]);
        GLDS(Ah + offA1 + ko, &lA[buf][0][q1 * 8]);
        GLDS(Al + offA1 + ko, &lA[buf][1][q1 * 8]);
        GLDS(Bh + offB1 + ko, &lB[buf][0][q1 * 8]);
        GLDS(Bl + offB1 + ko, &lB[buf][1][q1 * 8]);
    };

    stage(0, 0);
    const int nK = DK / BKS;  // 128
    for (int kt = 0; kt < nK; ++kt) {
        const int cur = kt & 1;
        if (kt + 1 < nK) {
            stage(cur ^ 1, kt + 1);                          // 8 loads in flight
            asm volatile("s_waitcnt vmcnt(8)" ::: "memory"); // cur's 8 done, next's 8 fly
        } else {
            asm volatile("s_waitcnt vmcnt(0)" ::: "memory");
        }
        __builtin_amdgcn_s_barrier();  // cur tile ready for all waves

        short8 bh[4], bl[4];
#pragma unroll
        for (int n = 0; n < 4; ++n) {
            bh[n] = *(const short8*)&lB[cur][0][boff[n]];
            bl[n] = *(const short8*)&lB[cur][1][boff[n]];
        }
#pragma unroll
        for (int m = 0; m < 8; ++m) {
            const short8 ah = *(const short8*)&lA[cur][0][aoff[m]];
            const short8 al = *(const short8*)&lA[cur][1][aoff[m]];
#pragma unroll
            for (int n = 0; n < 4; ++n) {
                acc[m][n] = __builtin_amdgcn_mfma_f32_16x16x32_bf16(ah, bh[n], acc[m][n], 0, 0, 0);
                acc[m][n] = __builtin_amdgcn_mfma_f32_16x16x32_bf16(ah, bl[n], acc[m][n], 0, 0, 0);
                acc[m][n] = __builtin_amdgcn_mfma_f32_16x16x32_bf16(al, bh[n], acc[m][n], 0, 0, 0);
            }
        }
        __builtin_amdgcn_s_barrier();  // all waves done reading cur before overwrite
    }

    // epilogue: C/D layout col=lane&15, row=(lane>>4)*4+j [m89]
    // per-row argmax over this block's 64-col wave strip -> cand[row][bx*4+wn]
    const int rowb = by * 256 + wm * 128;
#pragma unroll
    for (int m = 0; m < 8; ++m) {
#pragma unroll
        for (int j = 0; j < 4; ++j) {
            float best = acc[m][0][j];
            int bidx = wn * 64 + r0;
#pragma unroll
            for (int n = 1; n < 4; ++n) {
                const float v = acc[m][n][j];
                const int c = wn * 64 + n * 16 + r0;
                if (v > best) { best = v; bidx = c; }
            }
#pragma unroll
            for (int off = 1; off < 16; off <<= 1) {
                const float ov = __shfl_xor(best, off, 64);
                const int oi = __shfl_xor(bidx, off, 64);
                if (ov > best || (ov == best && oi < bidx)) { best = ov; bidx = oi; }
            }
            const int row = rowb + m * 16 + rg * 4 + j;
            if (r0 == 0)
                cand[(size_t)row * 16 + bx * 4 + wn] = make_float2(best, (float)(bx * 256 + bidx));
            if (bx == 0 && wn == 0 && r0 < 2) s01[row * 2 + r0] = acc[m][0][j];
        }
    }
}

// ---------------- final reduce: 16 candidates/row + eta ----------------
__global__ void __launch_bounds__(256) finalize_kernel(const float2* __restrict__ cand,
                                                       const float* __restrict__ s01,
                                                       float* __restrict__ out) {
    const int row = blockIdx.x * 256 + threadIdx.x;
    const float2* c = cand + (size_t)row * 16;
    float best = c[0].x;
    float bi = c[0].y;
#pragma unroll
    for (int i = 1; i < 16; ++i) {
        const float2 p = c[i];
        if (p.x > best) { best = p.x; bi = p.y; }  // ascending col blocks: strict > keeps first
    }
    out[row] = bi;
    out[NQ + row] = (s01[row * 2 + 1] - s01[row * 2 + 0]) * 0.25f + 0.5f;
}

extern "C" void kernel_launch(void* const* d_in, const int* in_sizes, int n_in,
                              void* d_out, int out_size, void* d_ws, size_t ws_size,
                              hipStream_t stream) {
    const float* hvs = (const float*)d_in[0];  // [16384,4096] f32
    const float* am  = (const float*)d_in[1];  // [1024,4096] f32
    float* out = (float*)d_out;                // [preds | eta]

    ushort_t* Bh = (ushort_t*)d_ws;
    ushort_t* Bl = Bh + (size_t)NC * DK;
    ushort_t* Ah = Bl + (size_t)NC * DK;
    ushort_t* Al = Ah + (size_t)NQ * DK;
    float2* cand = (float2*)(Al + (size_t)NQ * DK);   // 16384*16 float2 = 2 MB
    float* s01 = (float*)(cand + (size_t)NQ * 16);    // 16384*2 f32

    norm_split_kernel<<<NC, 256, 0, stream>>>(am, Bh, Bl);
    norm_split_kernel<<<NQ, 256, 0, stream>>>(hvs, Ah, Al);
    gemm_fused_kernel<<<256, 512, 0, stream>>>(Ah, Al, Bh, Bl, cand, s01);
    finalize_kernel<<<NQ / 256, 256, 0, stream>>>(cand, s01, out);
}